// Round 3
// baseline (70.164 us; speedup 1.0000x reference)
//
#include <hip/hip_runtime.h>
#include <hip/hip_fp16.h>

#define NATOM 8192
#define FR    128
#define LH1   128
#define LH2   64
#define NSEG  64
#define PB    256     // pair-kernel blocks
#define PT    1024    // pair-kernel threads/block
#define PPT   16      // pairs per thread
#define AB1   8       // atoms per block, k_l1 / k_l23

// fast tanh: 1 - 2/(e^{2x}+1); saturates to +-1 for large |x| (inf-safe)
__device__ __forceinline__ float fast_tanh(float x)
{
    float t = __expf(2.f * x);
    return 1.f - 2.f * __builtin_amdgcn_rcpf(t + 1.f);
}

// ---------------- kernel A: layer 1 for both MLPs ----------------
// grid 1024 x 256. Block handles 8 atoms. lane tid = output col in [0,256):
// tid<128 -> sigma path col tid, else eps path col tid-128. Per k: weight is a
// coalesced per-lane vector load; r[a][k] is block-uniform -> s_load feeding 8
// independent fma chains (acc[8]). Writes h1 [NATOM][256] f32 (row-major).
__global__ __launch_bounds__(256) void k_l1(
    const float* __restrict__ r,
    const float* __restrict__ w1s, const float* __restrict__ b1s,
    const float* __restrict__ w1e, const float* __restrict__ b1e,
    float* __restrict__ h1out)
{
    const int tid  = threadIdx.x;
    const int path = tid >> 7;          // wave-uniform (waves 0,1 vs 2,3)
    const int col  = tid & 127;
    const float* __restrict__ W = path ? w1e : w1s;   // [128 k][128 col]
    const float* __restrict__ B = path ? b1e : b1s;
    const int a0 = blockIdx.x * AB1;
    const float* __restrict__ rb = r + (size_t)a0 * FR;

    float acc[AB1];
#pragma unroll
    for (int a = 0; a < AB1; ++a) acc[a] = 0.f;

#pragma unroll 4
    for (int k = 0; k < FR; ++k) {
        float w = W[k * 128 + col];               // coalesced vector load
#pragma unroll
        for (int a = 0; a < AB1; ++a)
            acc[a] = fmaf(rb[a * FR + k], w, acc[a]);  // rb uniform -> s_load
    }

    float bv = B[col];
    float* __restrict__ ho = h1out + (size_t)a0 * 256 + tid;
#pragma unroll
    for (int a = 0; a < AB1; ++a)
        ho[a * 256] = fast_tanh(acc[a] + bv);     // coalesced stores
}

// ---------------- kernel B: layers 2+3 ----------------
// grid 1024 x 256. Block handles 8 atoms. lane: c2 = tid&63, path = (tid>>6)&1,
// khalf = tid>>7. Weights coalesced per-lane; h1 rows uniform -> s_load.
// k-halves combined via padded LDS; layer-3 dot via wave shfl reduce.
__global__ __launch_bounds__(256) void k_l23(
    const float* __restrict__ h1,
    const float* __restrict__ w2s, const float* __restrict__ b2s,
    const float* __restrict__ w3s, const float* __restrict__ b3s,
    const float* __restrict__ w2e, const float* __restrict__ b2e,
    const float* __restrict__ w3e, const float* __restrict__ b3e,
    float* __restrict__ sig15, float* __restrict__ qv)
{
    const int tid  = threadIdx.x;
    const int c2   = tid & 63;
    const int path = (tid >> 6) & 1;    // wave-uniform
    const int kh   = tid >> 7;          // wave-uniform
    const float* __restrict__ W2 = path ? w2e : w2s;   // [128 k][64 c2]
    const int a0 = blockIdx.x * AB1;
    // this wave's quarter of h1: path offset + k-half offset
    const float* __restrict__ hb = h1 + (size_t)a0 * 256 + path * 128 + kh * 64;

    float acc[AB1];
#pragma unroll
    for (int a = 0; a < AB1; ++a) acc[a] = 0.f;

#pragma unroll 4
    for (int k = 0; k < 64; ++k) {
        float w = W2[(kh * 64 + k) * LH2 + c2];   // coalesced vector load
#pragma unroll
        for (int a = 0; a < AB1; ++a)
            acc[a] = fmaf(hb[a * 256 + k], w, acc[a]);  // hb uniform -> s_load
    }

    __shared__ float part[128][AB1 + 1];   // +1 pad -> conflict-free reads
    if (kh == 1) {
#pragma unroll
        for (int a = 0; a < AB1; ++a) part[tid - 128][a] = acc[a];
    }
    __syncthreads();
    if (kh == 0) {
        const float* __restrict__ B2 = path ? b2e : b2s;
        const float* __restrict__ W3 = path ? w3e : w3s;
        const float b3v = path ? b3e[0] : b3s[0];
        const float w3v = W3[c2];
        const float b2v = B2[c2];
#pragma unroll
        for (int a = 0; a < AB1; ++a) {
            float h2 = fast_tanh(acc[a] + part[tid][a] + b2v);
            float t = h2 * w3v;
#pragma unroll
            for (int o = 32; o; o >>= 1) t += __shfl_xor(t, o);
            if (c2 == a) {                 // lane a writes atom a0+a
                float m = t + b3v;
                if (path == 0) {
                    float sg = fmaf(10.f * m, m, 4.f);       // sigma = 4 + 10 m^2
                    sig15[a0 + a] = sg * sqrtf(sg);          // sigma^1.5
                } else {
                    qv[a0 + a] = 0.31622776601683794f * fabsf(m); // sqrt(eps)
                }
            }
        }
    }
}

// ---------------- fallback fused MLP (only if ws_size is tiny) ----------------
__global__ __launch_bounds__(512) void k_mlp_fb(
    const float* __restrict__ r,
    const float* __restrict__ w1s, const float* __restrict__ b1s,
    const float* __restrict__ w2s, const float* __restrict__ b2s,
    const float* __restrict__ w3s, const float* __restrict__ b3s,
    const float* __restrict__ w1e, const float* __restrict__ b1e,
    const float* __restrict__ w2e, const float* __restrict__ b2e,
    const float* __restrict__ w3e, const float* __restrict__ b3e,
    float* __restrict__ sig15, float* __restrict__ qv)
{
    const int path = blockIdx.y;
    const float* __restrict__ w1 = path ? w1e : w1s;
    const float* __restrict__ b1 = path ? b1e : b1s;
    const float* __restrict__ w2 = path ? w2e : w2s;
    const float* __restrict__ b2 = path ? b2e : b2s;
    const float* __restrict__ w3 = path ? w3e : w3s;
    const float* __restrict__ b3 = path ? b3e : b3s;
    const int tid  = threadIdx.x;
    const int lane = tid & 63;
    const int wv   = __builtin_amdgcn_readfirstlane(tid >> 6);
    __shared__ float rT[FR * 64];
    __shared__ float p3s[8][64];
    {
        const float4* rp = (const float4*)(r + (size_t)blockIdx.x * 64 * FR);
#pragma unroll
        for (int i = 0; i < 4; ++i) {
            int f = i * 512 + tid;
            float4 v = rp[f];
            int atom = f >> 5, k0 = (f & 31) * 4, sw = f & 31;
            rT[(k0 + 0) * 64 + (atom ^ sw)] = v.x;
            rT[(k0 + 1) * 64 + (atom ^ sw)] = v.y;
            rT[(k0 + 2) * 64 + (atom ^ sw)] = v.z;
            rT[(k0 + 3) * 64 + (atom ^ sw)] = v.w;
        }
    }
    __syncthreads();
    float acc[16];
#pragma unroll
    for (int ci = 0; ci < 16; ++ci) acc[ci] = 0.f;
    {
        const float* __restrict__ w1p = w1 + wv * 16;
#pragma unroll 4
        for (int k = 0; k < FR; ++k) {
            float rv = rT[k * 64 + (lane ^ (k >> 2))];
            const float* __restrict__ wk = w1p + k * LH1;
#pragma unroll
            for (int ci = 0; ci < 16; ++ci) acc[ci] = fmaf(rv, wk[ci], acc[ci]);
        }
    }
    __syncthreads();
#pragma unroll
    for (int ci = 0; ci < 16; ++ci) {
        int c = wv * 16 + ci;
        rT[c * 64 + lane] = fast_tanh(acc[ci] + b1[c]);
    }
    __syncthreads();
    float acc2[8];
#pragma unroll
    for (int ci = 0; ci < 8; ++ci) acc2[ci] = 0.f;
#pragma unroll 4
    for (int k = 0; k < LH1; ++k) {
        float hv = rT[k * 64 + lane];
        const float* __restrict__ wk = w2 + k * LH2 + wv * 8;
#pragma unroll
        for (int ci = 0; ci < 8; ++ci) acc2[ci] = fmaf(hv, wk[ci], acc2[ci]);
    }
    float p3 = 0.f;
#pragma unroll
    for (int ci = 0; ci < 8; ++ci) {
        int c = wv * 8 + ci;
        p3 = fmaf(fast_tanh(acc2[ci] + b2[c]), w3[c], p3);
    }
    p3s[wv][lane] = p3;
    __syncthreads();
    if (wv == 0) {
        float m = (((p3s[0][lane] + p3s[1][lane]) + (p3s[2][lane] + p3s[3][lane]))
                +  ((p3s[4][lane] + p3s[5][lane]) + (p3s[6][lane] + p3s[7][lane]))) + b3[0];
        int a = blockIdx.x * 64 + lane;
        if (path == 0) {
            float sg = fmaf(10.f * m, m, 4.f);
            sig15[a] = sg * sqrtf(sg);
        } else {
            qv[a] = 0.31622776601683794f * fabsf(m);
        }
    }
}

// ---------------- kernel 2: pair energies ----------------
__device__ __forceinline__ float pair_e(const float4* atomd, int ia, int ib)
{
    float4 A = atomd[ia], B = atomd[ib];
    float dx = A.x - B.x, dy = A.y - B.y, dz = A.z - B.z;
    float D2 = fmaf(dx, dx, fmaf(dy, dy, dz * dz));
    float inv = __builtin_amdgcn_rcpf(D2);
    float inv3 = inv * inv * inv;
    __half2 ha = __builtin_bit_cast(__half2, A.w);
    __half2 hb = __builtin_bit_cast(__half2, B.w);
    float pp = __low2float(ha) * __low2float(hb);    // sig_i^1.5 * sig_j^1.5
    float qq = __high2float(ha) * __high2float(hb);  // eps_mixed
    float s6 = pp * pp * inv3;                       // (sig_i*sig_j)^3 / D2^3
    return 4.f * qq * (s6 * s6 - s6);
}

__global__ __launch_bounds__(PT, 1) void k_pair(
    const float* __restrict__ xyz, const int* __restrict__ pairs,
    const int* __restrict__ num_pairs,
    const float* __restrict__ sig15, const float* __restrict__ qv,
    float* __restrict__ blocksums, int P)
{
    extern __shared__ char smem[];
    float4* atomd = (float4*)smem;                         // 8192 * 16B = 128 KiB
    int*    off   = (int*)(smem + NATOM * 16);             // 65 ints (+pad)
    float*  bsum  = (float*)(smem + NATOM * 16 + 68 * 4);  // 64 floats

    const int tid = threadIdx.x;

    for (int i = tid; i < NATOM; i += PT) {
        float x = xyz[3 * i], y = xyz[3 * i + 1], z = xyz[3 * i + 2];
        __half2 pq = __halves2half2(__float2half(sig15[i]), __float2half(qv[i]));
        atomd[i] = make_float4(x, y, z, __builtin_bit_cast(float, pq));
    }
    if (tid < NSEG) { off[tid + 1] = num_pairs[tid]; bsum[tid] = 0.f; }
    if (tid == PT - 1) off[0] = 0;
    __syncthreads();
    if (tid == 0) { int run = 0; for (int b = 1; b <= NSEG; ++b) { run += off[b]; off[b] = run; } }
    __syncthreads();

    const int base = (blockIdx.x * PT + tid) * PPT;
    const bool fast = (base + PPT <= P);

    if (__all(fast)) {
        int pr2[PPT * 2];
        const int4* pp4 = (const int4*)(pairs + (size_t)base * 2);
#pragma unroll
        for (int i = 0; i < PPT / 2; ++i) {
            int4 v = pp4[i];
            pr2[4*i] = v.x; pr2[4*i+1] = v.y; pr2[4*i+2] = v.z; pr2[4*i+3] = v.w;
        }
        int s = 0;
#pragma unroll
        for (int st = 32; st; st >>= 1) { int ns = s + st; if (ns <= NSEG - 1 && off[ns] <= base) s = ns; }
        int off_next = off[s + 1];
        float acc = 0.f;
#pragma unroll
        for (int i = 0; i < PPT; ++i) {
            int idx = base + i;
            while (s < NSEG - 1 && idx >= off_next) {
                if (acc != 0.f) atomicAdd(&bsum[s], acc);
                acc = 0.f; ++s; off_next = off[s + 1];
            }
            acc += pair_e(atomd, pr2[2 * i], pr2[2 * i + 1]);
        }
        int s0 = __builtin_amdgcn_readfirstlane(s);
        if (__all(s == s0)) {
            float v = acc;
#pragma unroll
            for (int o = 32; o; o >>= 1) v += __shfl_xor(v, o);
            if ((tid & 63) == 0) atomicAdd(&bsum[s0], v);
        } else {
            atomicAdd(&bsum[s], acc);
        }
    } else if (base < P) {
        int s = 0;
#pragma unroll
        for (int st = 32; st; st >>= 1) { int ns = s + st; if (ns <= NSEG - 1 && off[ns] <= base) s = ns; }
        int off_next = off[s + 1];
        float acc = 0.f;
        for (int i = 0; i < PPT; ++i) {
            int idx = base + i;
            if (idx >= P) break;
            while (s < NSEG - 1 && idx >= off_next) {
                if (acc != 0.f) atomicAdd(&bsum[s], acc);
                acc = 0.f; ++s; off_next = off[s + 1];
            }
            acc += pair_e(atomd, pairs[2 * (size_t)idx], pairs[2 * (size_t)idx + 1]);
        }
        if (acc != 0.f) atomicAdd(&bsum[s], acc);
    }
    __syncthreads();
    if (tid < NSEG) blocksums[blockIdx.x * NSEG + tid] = bsum[tid];
}

// ---------------- kernel 3: deterministic final reduce ----------------
__global__ __launch_bounds__(256) void k_reduce(const float* __restrict__ bs, float* __restrict__ out)
{
    __shared__ float red[4][NSEG];
    int b = threadIdx.x & 63, part = threadIdx.x >> 6;
    float s = 0.f;
    for (int j = part; j < PB; j += 4) s += bs[(size_t)j * NSEG + b];
    red[part][b] = s;
    __syncthreads();
    if (threadIdx.x < NSEG) out[b] = (red[0][b] + red[1][b]) + (red[2][b] + red[3][b]);
}

extern "C" void kernel_launch(void* const* d_in, const int* in_sizes, int n_in,
                              void* d_out, int out_size, void* d_ws, size_t ws_size,
                              hipStream_t stream)
{
    const float* r    = (const float*)d_in[0];
    const float* xyz  = (const float*)d_in[1];
    const int*   prs  = (const int*)d_in[2];
    const int*   np   = (const int*)d_in[3];
    const float* sW1  = (const float*)d_in[4];
    const float* sb1  = (const float*)d_in[5];
    const float* sW2  = (const float*)d_in[6];
    const float* sb2  = (const float*)d_in[7];
    const float* sW3  = (const float*)d_in[8];
    const float* sb3  = (const float*)d_in[9];
    const float* eW1  = (const float*)d_in[10];
    const float* eb1  = (const float*)d_in[11];
    const float* eW2  = (const float*)d_in[12];
    const float* eb2  = (const float*)d_in[13];
    const float* eW3  = (const float*)d_in[14];
    const float* eb3  = (const float*)d_in[15];
    float* out = (float*)d_out;
    float* ws  = (float*)d_ws;
    const int P = in_sizes[2] / 2;

    const size_t need = ((size_t)NATOM * 256 + NATOM + NATOM + (size_t)PB * NSEG) * 4;
    float *sig15, *qvv, *bsums;
    if (ws_size >= need) {
        float* h1 = ws;                       // 8192*256 f32
        sig15 = ws + (size_t)NATOM * 256;
        qvv   = sig15 + NATOM;
        bsums = qvv + NATOM;
        k_l1<<<NATOM / AB1, 256, 0, stream>>>(r, sW1, sb1, eW1, eb1, h1);
        k_l23<<<NATOM / AB1, 256, 0, stream>>>(h1, sW2, sb2, sW3, sb3,
                                               eW2, eb2, eW3, eb3, sig15, qvv);
    } else {
        sig15 = ws; qvv = ws + NATOM; bsums = ws + 2 * NATOM;
        k_mlp_fb<<<dim3(NATOM / 64, 2), 512, 0, stream>>>(
            r, sW1, sb1, sW2, sb2, sW3, sb3, eW1, eb1, eW2, eb2, eW3, eb3, sig15, qvv);
    }

    size_t smem = (size_t)NATOM * 16 + 68 * 4 + NSEG * 4;   // 131,600 B
    hipFuncSetAttribute((const void*)k_pair, hipFuncAttributeMaxDynamicSharedMemorySize, (int)smem);
    k_pair<<<PB, PT, smem, stream>>>(xyz, prs, np, sig15, qvv, bsums, P);
    k_reduce<<<1, 256, 0, stream>>>(bsums, out);
}

// Round 4
// 54.649 us; speedup vs baseline: 1.2839x; 1.2839x over previous
//
#include <hip/hip_runtime.h>
#include <hip/hip_fp16.h>

#define NATOM 8192
#define FR    128
#define LH2   64
#define NSEG  64
#define PB    256     // pair-kernel blocks
#define PT    1024    // pair-kernel threads/block
#define PPT   16      // pairs per thread

// fast tanh: 1 - 2/(e^{2x}+1); saturates to +-1 for large |x| (inf-safe)
__device__ __forceinline__ float fast_tanh(float x)
{
    float t = __expf(2.f * x);
    return 1.f - 2.f * __builtin_amdgcn_rcpf(t + 1.f);
}

// ---------------- kernel 1: layer 1, both paths, GEMM-style ----------------
// grid 256 x 1024. Block: 32 atoms x 256 cols (cols 0-127 = sigma, 128-255 = eps).
// Thread tile: 2 cols x 4 atoms. A (r rows) from LDS via wave-uniform
// ds_read_b128 broadcast; W per-lane coalesced float2 from L2. No scalar-path
// operand feeds (rounds 1-3 showed s_load-fed inner loops run at <15% VALU).
__global__ __launch_bounds__(1024) void k_g1(
    const float* __restrict__ r,
    const float* __restrict__ w1s, const float* __restrict__ b1s,
    const float* __restrict__ w1e, const float* __restrict__ b1e,
    float* __restrict__ h1)
{
    __shared__ float rT[32][FR];            // 16 KB
    const int tid = threadIdx.x;
    const int cg  = tid & 127;              // col group (x2 cols)
    const int ag  = tid >> 7;               // atom group (x4 atoms), wave-uniform
    const int a0  = blockIdx.x * 32;

    // stage 32 r-rows: 4096 floats = 1024 float4 = exactly 1 per thread
    ((float4*)&rT[0][0])[tid] = ((const float4*)(r + (size_t)a0 * FR))[tid];
    __syncthreads();

    const int c    = cg * 2;                // even col in [0,256)
    const int path = c >> 7;                // wave-uniform (64 cg per wave)
    const float* __restrict__ W = path ? w1e : w1s;   // [128 k][128 col]
    const float* __restrict__ B = path ? b1e : b1s;
    const int c1 = c & 127;
    const float* __restrict__ Ar = &rT[ag * 4][0];

    float acc[2][4];
#pragma unroll
    for (int i = 0; i < 2; ++i)
#pragma unroll
        for (int a = 0; a < 4; ++a) acc[i][a] = 0.f;

#pragma unroll 2
    for (int k = 0; k < FR; k += 4) {
        float Av[4][4];
#pragma unroll
        for (int a = 0; a < 4; ++a) {
            float4 t = *(const float4*)(Ar + a * FR + k);   // ds_read_b128 broadcast
            Av[a][0] = t.x; Av[a][1] = t.y; Av[a][2] = t.z; Av[a][3] = t.w;
        }
        float wx[4], wy[4];
#pragma unroll
        for (int j = 0; j < 4; ++j) {
            float2 w = *(const float2*)(W + (size_t)(k + j) * 128 + c1);  // coalesced
            wx[j] = w.x; wy[j] = w.y;
        }
#pragma unroll
        for (int j = 0; j < 4; ++j)
#pragma unroll
            for (int a = 0; a < 4; ++a) {
                acc[0][a] = fmaf(Av[a][j], wx[j], acc[0][a]);
                acc[1][a] = fmaf(Av[a][j], wy[j], acc[1][a]);
            }
    }

    const float b0 = B[c1], b1v = B[c1 + 1];
#pragma unroll
    for (int a = 0; a < 4; ++a) {
        float2 o;
        o.x = fast_tanh(acc[0][a] + b0);
        o.y = fast_tanh(acc[1][a] + b1v);
        *(float2*)(h1 + (size_t)(a0 + ag * 4 + a) * 256 + c) = o;   // coalesced
    }
}

// ---------------- kernel 2: layers 2+3 + pack atom record ----------------
// grid 256 x 512. Block: 32 atoms x 128 cols (64 c2 x 2 paths; lanes 0-31 sigma,
// 32-63 eps). Same GEMM operand pattern. Final 64-dot via shfl_xor butterfly in
// 32-lane halves, then xor-32 exchange; lane 0 of each wave packs+writes float4.
__global__ __launch_bounds__(512) void k_g23(
    const float* __restrict__ h1, const float* __restrict__ xyz,
    const float* __restrict__ w2s, const float* __restrict__ b2s,
    const float* __restrict__ w3s, const float* __restrict__ b3s,
    const float* __restrict__ w2e, const float* __restrict__ b2e,
    const float* __restrict__ w3e, const float* __restrict__ b3e,
    float4* __restrict__ atomd)
{
    __shared__ float hT[32][256];           // 32 KB
    const int tid = threadIdx.x;
    const int cg  = tid & 63;
    const int ag  = tid >> 6;               // wave-uniform
    const int a0  = blockIdx.x * 32;

    // stage 32 h1-rows: 8192 floats = 2048 float4 / 512 thr = 4 each
    {
        const float4* hp = (const float4*)(h1 + (size_t)a0 * 256);
        float4* ht = (float4*)&hT[0][0];
#pragma unroll
        for (int i = 0; i < 4; ++i) ht[i * 512 + tid] = hp[i * 512 + tid];
    }
    __syncthreads();

    const int c    = cg * 2;                // [0,128)
    const int path = c >> 6;                // lanes 0-31: 0, lanes 32-63: 1
    const int c2   = c & 63;
    const float* __restrict__ W2 = path ? w2e : w2s;   // [128 k][64 c]
    const int poff = path * 128;
    const float* __restrict__ Ah = &hT[ag * 4][0];

    float acc[2][4];
#pragma unroll
    for (int i = 0; i < 2; ++i)
#pragma unroll
        for (int a = 0; a < 4; ++a) acc[i][a] = 0.f;

#pragma unroll 2
    for (int k = 0; k < FR; k += 4) {
        float Av[4][4];
#pragma unroll
        for (int a = 0; a < 4; ++a) {
            float4 t = *(const float4*)(Ah + a * 256 + poff + k);  // 2-addr broadcast
            Av[a][0] = t.x; Av[a][1] = t.y; Av[a][2] = t.z; Av[a][3] = t.w;
        }
        float wx[4], wy[4];
#pragma unroll
        for (int j = 0; j < 4; ++j) {
            float2 w = *(const float2*)(W2 + (size_t)(k + j) * LH2 + c2); // coalesced
            wx[j] = w.x; wy[j] = w.y;
        }
#pragma unroll
        for (int j = 0; j < 4; ++j)
#pragma unroll
            for (int a = 0; a < 4; ++a) {
                acc[0][a] = fmaf(Av[a][j], wx[j], acc[0][a]);
                acc[1][a] = fmaf(Av[a][j], wy[j], acc[1][a]);
            }
    }

    const float* __restrict__ B2 = path ? b2e : b2s;
    const float* __restrict__ W3 = path ? w3e : w3s;
    const float b2v0 = B2[c2], b2v1 = B2[c2 + 1];
    const float w3v0 = W3[c2], w3v1 = W3[c2 + 1];

    float tsum[4];
#pragma unroll
    for (int a = 0; a < 4; ++a) {
        float h20 = fast_tanh(acc[0][a] + b2v0);
        float h21 = fast_tanh(acc[1][a] + b2v1);
        tsum[a] = fmaf(h20, w3v0, h21 * w3v1);
    }
    // butterfly within 32-lane halves (per-path partial dots)
#pragma unroll
    for (int o = 1; o <= 16; o <<= 1)
#pragma unroll
        for (int a = 0; a < 4; ++a) tsum[a] += __shfl_xor(tsum[a], o);
    // exchange halves: lane L gets other path's sum
    float osum[4];
#pragma unroll
    for (int a = 0; a < 4; ++a) osum[a] = __shfl_xor(tsum[a], 32);

    if ((tid & 63) == 0) {                  // lane 0: tsum = sigma-sum, osum = eps-sum
        const float b3sv = b3s[0], b3ev = b3e[0];
#pragma unroll
        for (int a = 0; a < 4; ++a) {
            int atom = a0 + ag * 4 + a;
            float ms = tsum[a] + b3sv;
            float me = osum[a] + b3ev;
            float sg = fmaf(10.f * ms, ms, 4.f);            // sigma = 4 + 10 m^2
            float p  = sg * sqrtf(sg);                      // sigma^1.5
            float q  = 0.31622776601683794f * fabsf(me);    // sqrt(eps)
            __half2 pq = __halves2half2(__float2half(p), __float2half(q));
            atomd[atom] = make_float4(xyz[3 * atom], xyz[3 * atom + 1],
                                      xyz[3 * atom + 2], __builtin_bit_cast(float, pq));
        }
    }
}

// ---------------- kernel 3: pair energies ----------------
__device__ __forceinline__ float pair_e(const float4* atomd, int ia, int ib)
{
    float4 A = atomd[ia], B = atomd[ib];
    float dx = A.x - B.x, dy = A.y - B.y, dz = A.z - B.z;
    float D2 = fmaf(dx, dx, fmaf(dy, dy, dz * dz));
    float inv = __builtin_amdgcn_rcpf(D2);
    float inv3 = inv * inv * inv;
    __half2 ha = __builtin_bit_cast(__half2, A.w);
    __half2 hb = __builtin_bit_cast(__half2, B.w);
    float pp = __low2float(ha) * __low2float(hb);    // (sig_i*sig_j)^1.5
    float qq = __high2float(ha) * __high2float(hb);  // eps_mixed
    float s6 = pp * pp * inv3;                       // (sig_i*sig_j)^3 / D2^3
    return 4.f * qq * (s6 * s6 - s6);
}

__global__ __launch_bounds__(PT, 1) void k_pair(
    const float4* __restrict__ atomg, const int* __restrict__ pairs,
    const int* __restrict__ num_pairs,
    float* __restrict__ blocksums, int P)
{
    extern __shared__ char smem[];
    float4* atomd = (float4*)smem;                         // 8192 * 16B = 128 KiB
    int*    off   = (int*)(smem + NATOM * 16);             // 65 ints (+pad)
    float*  bsum  = (float*)(smem + NATOM * 16 + 68 * 4);  // 64 floats

    const int tid = threadIdx.x;

    // coalesced float4 stream of prepacked atom records
#pragma unroll
    for (int i = 0; i < NATOM / PT; ++i) atomd[i * PT + tid] = atomg[i * PT + tid];
    if (tid < NSEG) { off[tid + 1] = num_pairs[tid]; bsum[tid] = 0.f; }
    if (tid == PT - 1) off[0] = 0;
    __syncthreads();
    if (tid == 0) { int run = 0; for (int b = 1; b <= NSEG; ++b) { run += off[b]; off[b] = run; } }
    __syncthreads();

    const int base = (blockIdx.x * PT + tid) * PPT;
    const bool fast = (base + PPT <= P);

    if (__all(fast)) {
        int pr2[PPT * 2];
        const int4* pp4 = (const int4*)(pairs + (size_t)base * 2);
#pragma unroll
        for (int i = 0; i < PPT / 2; ++i) {
            int4 v = pp4[i];
            pr2[4*i] = v.x; pr2[4*i+1] = v.y; pr2[4*i+2] = v.z; pr2[4*i+3] = v.w;
        }
        int s = 0;
#pragma unroll
        for (int st = 32; st; st >>= 1) { int ns = s + st; if (ns <= NSEG - 1 && off[ns] <= base) s = ns; }
        int off_next = off[s + 1];
        float acc = 0.f;
#pragma unroll
        for (int i = 0; i < PPT; ++i) {
            int idx = base + i;
            while (s < NSEG - 1 && idx >= off_next) {   // segment boundary (rare)
                if (acc != 0.f) atomicAdd(&bsum[s], acc);
                acc = 0.f; ++s; off_next = off[s + 1];
            }
            acc += pair_e(atomd, pr2[2 * i], pr2[2 * i + 1]);
        }
        int s0 = __builtin_amdgcn_readfirstlane(s);
        if (__all(s == s0)) {
            float v = acc;
#pragma unroll
            for (int o = 32; o; o >>= 1) v += __shfl_xor(v, o);
            if ((tid & 63) == 0) atomicAdd(&bsum[s0], v);
        } else {
            atomicAdd(&bsum[s], acc);
        }
    } else if (base < P) {
        int s = 0;
#pragma unroll
        for (int st = 32; st; st >>= 1) { int ns = s + st; if (ns <= NSEG - 1 && off[ns] <= base) s = ns; }
        int off_next = off[s + 1];
        float acc = 0.f;
        for (int i = 0; i < PPT; ++i) {
            int idx = base + i;
            if (idx >= P) break;
            while (s < NSEG - 1 && idx >= off_next) {
                if (acc != 0.f) atomicAdd(&bsum[s], acc);
                acc = 0.f; ++s; off_next = off[s + 1];
            }
            acc += pair_e(atomd, pairs[2 * (size_t)idx], pairs[2 * (size_t)idx + 1]);
        }
        if (acc != 0.f) atomicAdd(&bsum[s], acc);
    }
    __syncthreads();
    if (tid < NSEG) blocksums[blockIdx.x * NSEG + tid] = bsum[tid];
}

// ---------------- kernel 4: deterministic final reduce ----------------
__global__ __launch_bounds__(512) void k_reduce(const float* __restrict__ bs, float* __restrict__ out)
{
    __shared__ float red[8][NSEG];
    int b = threadIdx.x & 63, part = threadIdx.x >> 6;
    float s = 0.f;
    for (int j = part; j < PB; j += 8) s += bs[(size_t)j * NSEG + b];
    red[part][b] = s;
    __syncthreads();
    if (threadIdx.x < NSEG) {
        float t = 0.f;
#pragma unroll
        for (int p = 0; p < 8; ++p) t += red[p][threadIdx.x];
        out[threadIdx.x] = t;
    }
}

extern "C" void kernel_launch(void* const* d_in, const int* in_sizes, int n_in,
                              void* d_out, int out_size, void* d_ws, size_t ws_size,
                              hipStream_t stream)
{
    const float* r    = (const float*)d_in[0];
    const float* xyz  = (const float*)d_in[1];
    const int*   prs  = (const int*)d_in[2];
    const int*   np   = (const int*)d_in[3];
    const float* sW1  = (const float*)d_in[4];
    const float* sb1  = (const float*)d_in[5];
    const float* sW2  = (const float*)d_in[6];
    const float* sb2  = (const float*)d_in[7];
    const float* sW3  = (const float*)d_in[8];
    const float* sb3  = (const float*)d_in[9];
    const float* eW1  = (const float*)d_in[10];
    const float* eb1  = (const float*)d_in[11];
    const float* eW2  = (const float*)d_in[12];
    const float* eb2  = (const float*)d_in[13];
    const float* eW3  = (const float*)d_in[14];
    const float* eb3  = (const float*)d_in[15];
    float* out = (float*)d_out;
    float* ws  = (float*)d_ws;
    const int P = in_sizes[2] / 2;

    float*  h1    = ws;                              // 8192*256 f32 = 8 MB
    float4* atomd = (float4*)(ws + (size_t)NATOM * 256);   // 8192 float4
    float*  bsums = ws + (size_t)NATOM * 256 + NATOM * 4;  // PB*64

    k_g1<<<NATOM / 32, 1024, 0, stream>>>(r, sW1, sb1, eW1, eb1, h1);
    k_g23<<<NATOM / 32, 512, 0, stream>>>(h1, xyz, sW2, sb2, sW3, sb3,
                                          eW2, eb2, eW3, eb3, atomd);

    size_t smem = (size_t)NATOM * 16 + 68 * 4 + NSEG * 4;   // 131,600 B
    hipFuncSetAttribute((const void*)k_pair, hipFuncAttributeMaxDynamicSharedMemorySize, (int)smem);
    k_pair<<<PB, PT, smem, stream>>>(atomd, prs, np, bsums, P);
    k_reduce<<<1, 512, 0, stream>>>(bsums, out);
}

// Round 5
// 54.472 us; speedup vs baseline: 1.2881x; 1.0032x over previous
//
#include <hip/hip_runtime.h>
#include <hip/hip_fp16.h>

#define NATOM 8192
#define FR    128
#define LH2   64
#define NSEG  64
#define PB    256     // pair-kernel blocks
#define PT    1024    // pair-kernel threads/block
#define PPT   16      // pairs per thread

// fast tanh: 1 - 2/(e^{2x}+1); saturates to +-1 for large |x| (inf-safe)
__device__ __forceinline__ float fast_tanh(float x)
{
    float t = __expf(2.f * x);
    return 1.f - 2.f * __builtin_amdgcn_rcpf(t + 1.f);
}

// ---------------- kernel 1: fully fused per-atom MLPs ----------------
// grid 256 x 1024 (16 waves). Block: 32 atoms. Layer1: thread = (col pair cg,
// atom group ag of 4); A from LDS wave-uniform ds_read_b128 broadcast, W
// per-lane coalesced float2 (both operands on the vector path). h1 stays in
// LDS (32KB) -> no global round trip. Layer2+3: wave = 2 atoms, lanes 0-31
// sigma / 32-63 eps, butterfly reduce, lane 0 packs float4 atom record.
__global__ __launch_bounds__(1024) void k_mlp_f(
    const float* __restrict__ r, const float* __restrict__ xyz,
    const float* __restrict__ w1s, const float* __restrict__ b1s,
    const float* __restrict__ w1e, const float* __restrict__ b1e,
    const float* __restrict__ w2s, const float* __restrict__ b2s,
    const float* __restrict__ w3s, const float* __restrict__ b3s,
    const float* __restrict__ w2e, const float* __restrict__ b2e,
    const float* __restrict__ w3e, const float* __restrict__ b3e,
    float4* __restrict__ atomd)
{
    __shared__ float rT[32][FR];      // 16 KB
    __shared__ float h1L[32][256];    // 32 KB
    const int tid = threadIdx.x;
    const int a0  = blockIdx.x * 32;

    // stage 32 r-rows: 4096 floats = 1024 float4 = exactly 1 per thread
    ((float4*)&rT[0][0])[tid] = ((const float4*)(r + (size_t)a0 * FR))[tid];
    __syncthreads();

    // ---- layer 1 ----
    {
        const int cg   = tid & 127;            // col pair
        const int ag   = tid >> 7;             // atom group of 4 (wave-uniform)
        const int c    = cg * 2;               // [0,256)
        const int path = c >> 7;               // wave-uniform
        const float* __restrict__ W = path ? w1e : w1s;   // [128 k][128 col]
        const float* __restrict__ B = path ? b1e : b1s;
        const int c1 = c & 127;
        const float* __restrict__ Ar = &rT[ag * 4][0];

        float acc[2][4];
#pragma unroll
        for (int i = 0; i < 2; ++i)
#pragma unroll
            for (int a = 0; a < 4; ++a) acc[i][a] = 0.f;

#pragma unroll 2
        for (int k = 0; k < FR; k += 4) {
            float Av[4][4];
#pragma unroll
            for (int a = 0; a < 4; ++a) {
                float4 t = *(const float4*)(Ar + a * FR + k);   // b128 broadcast
                Av[a][0] = t.x; Av[a][1] = t.y; Av[a][2] = t.z; Av[a][3] = t.w;
            }
            float wx[4], wy[4];
#pragma unroll
            for (int j = 0; j < 4; ++j) {
                float2 w = *(const float2*)(W + (size_t)(k + j) * 128 + c1);  // coalesced
                wx[j] = w.x; wy[j] = w.y;
            }
#pragma unroll
            for (int j = 0; j < 4; ++j)
#pragma unroll
                for (int a = 0; a < 4; ++a) {
                    acc[0][a] = fmaf(Av[a][j], wx[j], acc[0][a]);
                    acc[1][a] = fmaf(Av[a][j], wy[j], acc[1][a]);
                }
        }
        const float b0 = B[c1], b1v = B[c1 + 1];
#pragma unroll
        for (int a = 0; a < 4; ++a) {
            h1L[ag * 4 + a][c]     = fast_tanh(acc[0][a] + b0);
            h1L[ag * 4 + a][c + 1] = fast_tanh(acc[1][a] + b1v);
        }
    }
    __syncthreads();

    // ---- layers 2+3 ----
    {
        const int lane = tid & 63;
        const int aw   = tid >> 6;             // wave id: 2 atoms each
        const int path = lane >> 5;            // half-wave
        const int c2   = (lane & 31) * 2;      // [0,64)
        const int poff = path * 128;
        const float* __restrict__ W2 = path ? w2e : w2s;   // [128 k][64 col]

        float acc[2][2];
#pragma unroll
        for (int i = 0; i < 2; ++i)
#pragma unroll
            for (int a = 0; a < 2; ++a) acc[i][a] = 0.f;

        const float* __restrict__ Ah0 = &h1L[aw * 2][poff];
        const float* __restrict__ Ah1 = &h1L[aw * 2 + 1][poff];

#pragma unroll 2
        for (int k = 0; k < FR; k += 4) {
            float4 t0 = *(const float4*)(Ah0 + k);   // 2-addr broadcast
            float4 t1 = *(const float4*)(Ah1 + k);
            float A0[4] = {t0.x, t0.y, t0.z, t0.w};
            float A1[4] = {t1.x, t1.y, t1.z, t1.w};
            float wx[4], wy[4];
#pragma unroll
            for (int j = 0; j < 4; ++j) {
                float2 w = *(const float2*)(W2 + (size_t)(k + j) * LH2 + c2); // coalesced
                wx[j] = w.x; wy[j] = w.y;
            }
#pragma unroll
            for (int j = 0; j < 4; ++j) {
                acc[0][0] = fmaf(A0[j], wx[j], acc[0][0]);
                acc[1][0] = fmaf(A0[j], wy[j], acc[1][0]);
                acc[0][1] = fmaf(A1[j], wx[j], acc[0][1]);
                acc[1][1] = fmaf(A1[j], wy[j], acc[1][1]);
            }
        }

        const float* __restrict__ B2 = path ? b2e : b2s;
        const float* __restrict__ W3 = path ? w3e : w3s;
        const float b2v0 = B2[c2], b2v1 = B2[c2 + 1];
        const float w3v0 = W3[c2], w3v1 = W3[c2 + 1];

        float tsum[2];
#pragma unroll
        for (int a = 0; a < 2; ++a) {
            float h20 = fast_tanh(acc[0][a] + b2v0);
            float h21 = fast_tanh(acc[1][a] + b2v1);
            tsum[a] = fmaf(h20, w3v0, h21 * w3v1);
        }
#pragma unroll
        for (int o = 1; o <= 16; o <<= 1)
#pragma unroll
            for (int a = 0; a < 2; ++a) tsum[a] += __shfl_xor(tsum[a], o);
        float osum[2];
#pragma unroll
        for (int a = 0; a < 2; ++a) osum[a] = __shfl_xor(tsum[a], 32);

        if (lane == 0) {   // tsum = sigma-path sum, osum = eps-path sum
            const float b3sv = b3s[0], b3ev = b3e[0];
#pragma unroll
            for (int a = 0; a < 2; ++a) {
                int atom = a0 + aw * 2 + a;
                float ms = tsum[a] + b3sv;
                float me = osum[a] + b3ev;
                float sg = fmaf(10.f * ms, ms, 4.f);            // sigma = 4 + 10 m^2
                float p  = sg * sqrtf(sg);                      // sigma^1.5
                float q  = 0.31622776601683794f * fabsf(me);    // sqrt(eps)
                __half2 pq = __halves2half2(__float2half(p), __float2half(q));
                atomd[atom] = make_float4(xyz[3 * atom], xyz[3 * atom + 1],
                                          xyz[3 * atom + 2], __builtin_bit_cast(float, pq));
            }
        }
    }
}

// ---------------- kernel 2: pair energies ----------------
__device__ __forceinline__ float pair_e(const float4* atomd, int ia, int ib)
{
    float4 A = atomd[ia], B = atomd[ib];
    float dx = A.x - B.x, dy = A.y - B.y, dz = A.z - B.z;
    float D2 = fmaf(dx, dx, fmaf(dy, dy, dz * dz));
    float inv = __builtin_amdgcn_rcpf(D2);
    float inv3 = inv * inv * inv;
    __half2 ha = __builtin_bit_cast(__half2, A.w);
    __half2 hb = __builtin_bit_cast(__half2, B.w);
    float pp = __low2float(ha) * __low2float(hb);    // (sig_i*sig_j)^1.5
    float qq = __high2float(ha) * __high2float(hb);  // eps_mixed
    float s6 = pp * pp * inv3;                       // (sig_i*sig_j)^3 / D2^3
    return 4.f * qq * (s6 * s6 - s6);
}

__global__ __launch_bounds__(PT, 1) void k_pair(
    const float4* __restrict__ atomg, const int* __restrict__ pairs,
    const int* __restrict__ num_pairs,
    float* __restrict__ blocksums, int P)
{
    extern __shared__ char smem[];
    float4* atomd = (float4*)smem;                         // 8192 * 16B = 128 KiB
    int*    off   = (int*)(smem + NATOM * 16);             // 65 ints (+pad)
    float*  bsum  = (float*)(smem + NATOM * 16 + 68 * 4);  // 64 floats

    const int tid = threadIdx.x;

    // coalesced float4 stream of prepacked atom records
#pragma unroll
    for (int i = 0; i < NATOM / PT; ++i) atomd[i * PT + tid] = atomg[i * PT + tid];
    // wave-0 shfl inclusive scan of num_pairs (replaces serial LDS-latency chain)
    if (tid < 64) {
        int run = num_pairs[tid];
#pragma unroll
        for (int d = 1; d < 64; d <<= 1) {
            int o = __shfl_up(run, d);
            if (tid >= d) run += o;
        }
        off[tid + 1] = run;
        if (tid == 0) off[0] = 0;
        bsum[tid] = 0.f;
    }
    __syncthreads();

    const int base = (blockIdx.x * PT + tid) * PPT;
    const bool fast = (base + PPT <= P);

    if (__all(fast)) {
        int pr2[PPT * 2];
        const int4* pp4 = (const int4*)(pairs + (size_t)base * 2);
#pragma unroll
        for (int i = 0; i < PPT / 2; ++i) {
            int4 v = pp4[i];
            pr2[4*i] = v.x; pr2[4*i+1] = v.y; pr2[4*i+2] = v.z; pr2[4*i+3] = v.w;
        }
        int s = 0;
#pragma unroll
        for (int st = 32; st; st >>= 1) { int ns = s + st; if (ns <= NSEG - 1 && off[ns] <= base) s = ns; }
        float acc = 0.f;
        if (base + PPT <= off[s + 1] || s == NSEG - 1) {
            // whole chunk in one segment: no per-pair checks (common case)
#pragma unroll
            for (int i = 0; i < PPT; ++i)
                acc += pair_e(atomd, pr2[2 * i], pr2[2 * i + 1]);
        } else {
            int off_next = off[s + 1];
#pragma unroll
            for (int i = 0; i < PPT; ++i) {
                int idx = base + i;
                while (s < NSEG - 1 && idx >= off_next) {
                    if (acc != 0.f) atomicAdd(&bsum[s], acc);
                    acc = 0.f; ++s; off_next = off[s + 1];
                }
                acc += pair_e(atomd, pr2[2 * i], pr2[2 * i + 1]);
            }
        }
        int s0 = __builtin_amdgcn_readfirstlane(s);
        if (__all(s == s0)) {
            float v = acc;
#pragma unroll
            for (int o = 32; o; o >>= 1) v += __shfl_xor(v, o);
            if ((tid & 63) == 0) atomicAdd(&bsum[s0], v);
        } else {
            atomicAdd(&bsum[s], acc);
        }
    } else if (base < P) {
        int s = 0;
#pragma unroll
        for (int st = 32; st; st >>= 1) { int ns = s + st; if (ns <= NSEG - 1 && off[ns] <= base) s = ns; }
        int off_next = off[s + 1];
        float acc = 0.f;
        for (int i = 0; i < PPT; ++i) {
            int idx = base + i;
            if (idx >= P) break;
            while (s < NSEG - 1 && idx >= off_next) {
                if (acc != 0.f) atomicAdd(&bsum[s], acc);
                acc = 0.f; ++s; off_next = off[s + 1];
            }
            acc += pair_e(atomd, pairs[2 * (size_t)idx], pairs[2 * (size_t)idx + 1]);
        }
        if (acc != 0.f) atomicAdd(&bsum[s], acc);
    }
    __syncthreads();
    if (tid < NSEG) blocksums[blockIdx.x * NSEG + tid] = bsum[tid];
}

// ---------------- kernel 3: deterministic final reduce ----------------
__global__ __launch_bounds__(512) void k_reduce(const float* __restrict__ bs, float* __restrict__ out)
{
    __shared__ float red[8][NSEG];
    int b = threadIdx.x & 63, part = threadIdx.x >> 6;
    float s = 0.f;
    for (int j = part; j < PB; j += 8) s += bs[(size_t)j * NSEG + b];
    red[part][b] = s;
    __syncthreads();
    if (threadIdx.x < NSEG) {
        float t = 0.f;
#pragma unroll
        for (int p = 0; p < 8; ++p) t += red[p][threadIdx.x];
        out[threadIdx.x] = t;
    }
}

extern "C" void kernel_launch(void* const* d_in, const int* in_sizes, int n_in,
                              void* d_out, int out_size, void* d_ws, size_t ws_size,
                              hipStream_t stream)
{
    const float* r    = (const float*)d_in[0];
    const float* xyz  = (const float*)d_in[1];
    const int*   prs  = (const int*)d_in[2];
    const int*   np   = (const int*)d_in[3];
    const float* sW1  = (const float*)d_in[4];
    const float* sb1  = (const float*)d_in[5];
    const float* sW2  = (const float*)d_in[6];
    const float* sb2  = (const float*)d_in[7];
    const float* sW3  = (const float*)d_in[8];
    const float* sb3  = (const float*)d_in[9];
    const float* eW1  = (const float*)d_in[10];
    const float* eb1  = (const float*)d_in[11];
    const float* eW2  = (const float*)d_in[12];
    const float* eb2  = (const float*)d_in[13];
    const float* eW3  = (const float*)d_in[14];
    const float* eb3  = (const float*)d_in[15];
    float* out = (float*)d_out;
    float* ws  = (float*)d_ws;
    const int P = in_sizes[2] / 2;

    float4* atomd = (float4*)ws;                 // 8192 float4 = 128 KB
    float*  bsums = ws + NATOM * 4;              // PB*64 f32

    k_mlp_f<<<NATOM / 32, 1024, 0, stream>>>(r, xyz, sW1, sb1, eW1, eb1,
                                             sW2, sb2, sW3, sb3,
                                             eW2, eb2, eW3, eb3, atomd);

    size_t smem = (size_t)NATOM * 16 + 68 * 4 + NSEG * 4;   // 131,600 B
    hipFuncSetAttribute((const void*)k_pair, hipFuncAttributeMaxDynamicSharedMemorySize, (int)smem);
    k_pair<<<PB, PT, smem, stream>>>(atomd, prs, np, bsums, P);
    k_reduce<<<1, 512, 0, stream>>>(bsums, out);
}

// Round 6
// 44.092 us; speedup vs baseline: 1.5913x; 1.2354x over previous
//
#include <hip/hip_runtime.h>
#include <hip/hip_fp16.h>

#define NATOM 8192
#define FR    128
#define LH2   64
#define NSEG  64
#define PB    256     // pair-kernel blocks
#define PT    1024    // pair-kernel threads/block
#define PPT   16      // pairs per thread

// fast tanh: 1 - 2/(e^{2x}+1); saturates to +-1 for large |x| (inf-safe)
__device__ __forceinline__ float fast_tanh(float x)
{
    float t = __expf(2.f * x);
    return 1.f - 2.f * __builtin_amdgcn_rcpf(t + 1.f);
}

// ---------------- kernel 1: fused MLPs, W staged in LDS ----------------
// 256 blocks x 512 thr (8 waves), 32 atoms/block. All W traffic: one coalesced
// LDS staging per block (no per-wave L2 re-fetch). Inner loops read A as
// wave-uniform ds_read_b128 broadcasts and W as per-lane conflict-free LDS
// reads. Layer1: thread = (col-pair cg of 256 cols, atom-group ag of 8).
// Layer2+3: thread = (col-pair over 128 cols [2 paths], atom-group of 4),
// butterfly reduce, xor-32 path exchange (round-5 proven pattern).
__global__ __launch_bounds__(512) void k_mlp_f2(
    const float* __restrict__ r, const float* __restrict__ xyz,
    const float* __restrict__ w1s, const float* __restrict__ b1s,
    const float* __restrict__ w1e, const float* __restrict__ b1e,
    const float* __restrict__ w2s, const float* __restrict__ b2s,
    const float* __restrict__ w3s, const float* __restrict__ b3s,
    const float* __restrict__ w2e, const float* __restrict__ b2e,
    const float* __restrict__ w3e, const float* __restrict__ b3e,
    float4* __restrict__ atomd)
{
    extern __shared__ float lds[];
    float* rT   = lds;            // [32 atoms][128 k]           16 KB
    float* Wt   = lds + 4096;     // L1: [64 k][256 c] / L2: [128 k][128 c']  64 KB
    float* h1L  = lds + 20480;    // [32 atoms][256 c]           32 KB
    float* mArr = lds + 28672;    // [2][32]                     256 B

    const int tid = threadIdx.x;
    const int a0  = blockIdx.x * 32;

    // ---- stage r (32 rows = 1024 float4, 2/thread) + W1 tile 0 ----
    {
        const float4* rp = (const float4*)(r + (size_t)a0 * FR);
#pragma unroll
        for (int i = 0; i < 2; ++i)
            ((float4*)rT)[i * 512 + tid] = rp[i * 512 + tid];
    }
#pragma unroll
    for (int i = 0; i < 8; ++i) {        // W1 k-tile 0: [64][256] = 4096 f4
        int idx = i * 512 + tid;
        int row = idx >> 6, c = (idx & 63) * 4;
        float4 v = (c < 128) ? *(const float4*)(w1s + row * 128 + c)
                             : *(const float4*)(w1e + row * 128 + (c - 128));
        *(float4*)(Wt + row * 256 + c) = v;
    }
    __syncthreads();

    // ---- layer 1 ----
    const int cg = tid & 127;            // col pair: c = 2*cg in [0,256)
    const int ag = tid >> 7;             // atom group of 8 (wave-uniform)
    const int c  = cg * 2;
    float acc[2][8];
#pragma unroll
    for (int i = 0; i < 2; ++i)
#pragma unroll
        for (int a = 0; a < 8; ++a) acc[i][a] = 0.f;

#pragma unroll
    for (int kt = 0; kt < 2; ++kt) {
#pragma unroll 2
        for (int k4 = 0; k4 < 16; ++k4) {
            const float* ar = rT + (ag * 8) * FR + kt * 64 + k4 * 4;
            float Av[8][4];
#pragma unroll
            for (int a = 0; a < 8; ++a) {
                float4 t = *(const float4*)(ar + a * FR);   // uniform b128 bcast
                Av[a][0] = t.x; Av[a][1] = t.y; Av[a][2] = t.z; Av[a][3] = t.w;
            }
            float wx[4], wy[4];
            const float* wr = Wt + (k4 * 4) * 256 + c;
#pragma unroll
            for (int j = 0; j < 4; ++j) {                   // per-lane b64, 2-way free
                float2 w = *(const float2*)(wr + j * 256);
                wx[j] = w.x; wy[j] = w.y;
            }
#pragma unroll
            for (int j = 0; j < 4; ++j)
#pragma unroll
                for (int a = 0; a < 8; ++a) {
                    acc[0][a] = fmaf(Av[a][j], wx[j], acc[0][a]);
                    acc[1][a] = fmaf(Av[a][j], wy[j], acc[1][a]);
                }
        }
        __syncthreads();                 // Wt reads done
        if (kt == 0) {                   // stage W1 k-tile 1
#pragma unroll
            for (int i = 0; i < 8; ++i) {
                int idx = i * 512 + tid;
                int row = idx >> 6, cc = (idx & 63) * 4;
                float4 v = (cc < 128) ? *(const float4*)(w1s + (64 + row) * 128 + cc)
                                      : *(const float4*)(w1e + (64 + row) * 128 + (cc - 128));
                *(float4*)(Wt + row * 256 + cc) = v;
            }
            __syncthreads();
        }
    }

    // tanh + h1 to LDS; then stage W2 (both paths, [128 k][128 c']) into Wt
    {
        const int path = c >> 7;
        const float* B = path ? b1e : b1s;
        const int c1 = c & 127;
        const float b0 = B[c1], b1v = B[c1 + 1];
#pragma unroll
        for (int a = 0; a < 8; ++a) {
            float2 o;
            o.x = fast_tanh(acc[0][a] + b0);
            o.y = fast_tanh(acc[1][a] + b1v);
            *(float2*)(h1L + (ag * 8 + a) * 256 + c) = o;
        }
    }
#pragma unroll
    for (int i = 0; i < 8; ++i) {        // 16384 f = 4096 f4
        int idx = i * 512 + tid;
        int row = idx >> 5, cp = (idx & 31) * 4;
        float4 v = (cp < 64) ? *(const float4*)(w2s + row * 64 + cp)
                             : *(const float4*)(w2e + row * 64 + (cp - 64));
        *(float4*)(Wt + row * 128 + cp) = v;
    }
    __syncthreads();

    // ---- layers 2+3 ----
    {
        const int lane = tid & 63;
        const int ag4  = tid >> 6;           // 8 waves x 4 atoms
        const int cp   = lane * 2;           // [0,128): lanes 0-31 sigma, 32-63 eps
        const int path = cp >> 6;
        const int c2   = cp & 63;
        float acc2[2][4];
#pragma unroll
        for (int i = 0; i < 2; ++i)
#pragma unroll
            for (int a = 0; a < 4; ++a) acc2[i][a] = 0.f;

#pragma unroll 2
        for (int k4 = 0; k4 < 32; ++k4) {
            const float* ah = h1L + (ag4 * 4) * 256 + path * 128 + k4 * 4;
            float Av[4][4];
#pragma unroll
            for (int a = 0; a < 4; ++a) {
                float4 t = *(const float4*)(ah + a * 256);  // 2-addr bcast (free)
                Av[a][0] = t.x; Av[a][1] = t.y; Av[a][2] = t.z; Av[a][3] = t.w;
            }
            float wx[4], wy[4];
            const float* wr = Wt + (k4 * 4) * 128 + cp;
#pragma unroll
            for (int j = 0; j < 4; ++j) {                   // per-lane b64
                float2 w = *(const float2*)(wr + j * 128);
                wx[j] = w.x; wy[j] = w.y;
            }
#pragma unroll
            for (int j = 0; j < 4; ++j)
#pragma unroll
                for (int a = 0; a < 4; ++a) {
                    acc2[0][a] = fmaf(Av[a][j], wx[j], acc2[0][a]);
                    acc2[1][a] = fmaf(Av[a][j], wy[j], acc2[1][a]);
                }
        }

        const float* B2 = path ? b2e : b2s;
        const float* W3 = path ? w3e : w3s;
        const float b2v0 = B2[c2], b2v1 = B2[c2 + 1];
        const float w3v0 = W3[c2], w3v1 = W3[c2 + 1];
        const float b3sv = b3s[0], b3ev = b3e[0];

        float tsum[4];
#pragma unroll
        for (int a = 0; a < 4; ++a) {
            float h20 = fast_tanh(acc2[0][a] + b2v0);
            float h21 = fast_tanh(acc2[1][a] + b2v1);
            tsum[a] = fmaf(h20, w3v0, h21 * w3v1);
        }
#pragma unroll
        for (int o = 1; o <= 16; o <<= 1)
#pragma unroll
            for (int a = 0; a < 4; ++a) tsum[a] += __shfl_xor(tsum[a], o);
        float osum[4];
#pragma unroll
        for (int a = 0; a < 4; ++a) osum[a] = __shfl_xor(tsum[a], 32);

#pragma unroll
        for (int a = 0; a < 4; ++a)
            if (lane == a) {             // lanes 0-3: tsum=path0(sigma), osum=path1(eps)
                mArr[ag4 * 4 + a]      = tsum[a] + b3sv;
                mArr[32 + ag4 * 4 + a] = osum[a] + b3ev;
            }
    }
    __syncthreads();

    if (tid < 32) {
        int atom = a0 + tid;
        float ms = mArr[tid], me = mArr[32 + tid];
        float sg = fmaf(10.f * ms, ms, 4.f);            // sigma = 4 + 10 m^2
        float p  = sg * sqrtf(sg);                      // sigma^1.5
        float q  = 0.31622776601683794f * fabsf(me);    // sqrt(eps)
        __half2 pq = __halves2half2(__float2half(p), __float2half(q));
        atomd[atom] = make_float4(xyz[3 * atom], xyz[3 * atom + 1],
                                  xyz[3 * atom + 2], __builtin_bit_cast(float, pq));
    }
}

// ---------------- kernel 2: pair energies ----------------
__device__ __forceinline__ float pair_e(const float4* atomd, int ia, int ib)
{
    float4 A = atomd[ia], B = atomd[ib];
    float dx = A.x - B.x, dy = A.y - B.y, dz = A.z - B.z;
    float D2 = fmaf(dx, dx, fmaf(dy, dy, dz * dz));
    float inv = __builtin_amdgcn_rcpf(D2);
    float inv3 = inv * inv * inv;
    __half2 ha = __builtin_bit_cast(__half2, A.w);
    __half2 hb = __builtin_bit_cast(__half2, B.w);
    float pp = __low2float(ha) * __low2float(hb);    // (sig_i*sig_j)^1.5
    float qq = __high2float(ha) * __high2float(hb);  // eps_mixed
    float s6 = pp * pp * inv3;                       // (sig_i*sig_j)^3 / D2^3
    return 4.f * qq * (s6 * s6 - s6);
}

__global__ __launch_bounds__(PT, 1) void k_pair(
    const float4* __restrict__ atomg, const int* __restrict__ pairs,
    const int* __restrict__ num_pairs,
    float* __restrict__ blocksums, int P)
{
    extern __shared__ char smem[];
    float4* atomd = (float4*)smem;                         // 8192 * 16B = 128 KiB
    int*    off   = (int*)(smem + NATOM * 16);             // 65 ints (+pad)
    float*  bsum  = (float*)(smem + NATOM * 16 + 68 * 4);  // 64 floats

    const int tid = threadIdx.x;

#pragma unroll
    for (int i = 0; i < NATOM / PT; ++i) atomd[i * PT + tid] = atomg[i * PT + tid];
    if (tid < 64) {
        int run = num_pairs[tid];
#pragma unroll
        for (int d = 1; d < 64; d <<= 1) {
            int o = __shfl_up(run, d);
            if (tid >= d) run += o;
        }
        off[tid + 1] = run;
        if (tid == 0) off[0] = 0;
        bsum[tid] = 0.f;
    }
    __syncthreads();

    const int base = (blockIdx.x * PT + tid) * PPT;
    const bool fast = (base + PPT <= P);

    if (__all(fast)) {
        int pr2[PPT * 2];
        const int4* pp4 = (const int4*)(pairs + (size_t)base * 2);
#pragma unroll
        for (int i = 0; i < PPT / 2; ++i) {
            int4 v = pp4[i];
            pr2[4*i] = v.x; pr2[4*i+1] = v.y; pr2[4*i+2] = v.z; pr2[4*i+3] = v.w;
        }
        int s = 0;
#pragma unroll
        for (int st = 32; st; st >>= 1) { int ns = s + st; if (ns <= NSEG - 1 && off[ns] <= base) s = ns; }
        float acc = 0.f;
        if (base + PPT <= off[s + 1] || s == NSEG - 1) {
#pragma unroll
            for (int i = 0; i < PPT; ++i)
                acc += pair_e(atomd, pr2[2 * i], pr2[2 * i + 1]);
        } else {
            int off_next = off[s + 1];
#pragma unroll
            for (int i = 0; i < PPT; ++i) {
                int idx = base + i;
                while (s < NSEG - 1 && idx >= off_next) {
                    if (acc != 0.f) atomicAdd(&bsum[s], acc);
                    acc = 0.f; ++s; off_next = off[s + 1];
                }
                acc += pair_e(atomd, pr2[2 * i], pr2[2 * i + 1]);
            }
        }
        int s0 = __builtin_amdgcn_readfirstlane(s);
        if (__all(s == s0)) {
            float v = acc;
#pragma unroll
            for (int o = 32; o; o >>= 1) v += __shfl_xor(v, o);
            if ((tid & 63) == 0) atomicAdd(&bsum[s0], v);
        } else {
            atomicAdd(&bsum[s], acc);
        }
    } else if (base < P) {
        int s = 0;
#pragma unroll
        for (int st = 32; st; st >>= 1) { int ns = s + st; if (ns <= NSEG - 1 && off[ns] <= base) s = ns; }
        int off_next = off[s + 1];
        float acc = 0.f;
        for (int i = 0; i < PPT; ++i) {
            int idx = base + i;
            if (idx >= P) break;
            while (s < NSEG - 1 && idx >= off_next) {
                if (acc != 0.f) atomicAdd(&bsum[s], acc);
                acc = 0.f; ++s; off_next = off[s + 1];
            }
            acc += pair_e(atomd, pairs[2 * (size_t)idx], pairs[2 * (size_t)idx + 1]);
        }
        if (acc != 0.f) atomicAdd(&bsum[s], acc);
    }
    __syncthreads();
    if (tid < NSEG) blocksums[blockIdx.x * NSEG + tid] = bsum[tid];
}

// ---------------- kernel 3: deterministic final reduce ----------------
__global__ __launch_bounds__(512) void k_reduce(const float* __restrict__ bs, float* __restrict__ out)
{
    __shared__ float red[8][NSEG];
    int b = threadIdx.x & 63, part = threadIdx.x >> 6;
    float s = 0.f;
    for (int j = part; j < PB; j += 8) s += bs[(size_t)j * NSEG + b];
    red[part][b] = s;
    __syncthreads();
    if (threadIdx.x < NSEG) {
        float t = 0.f;
#pragma unroll
        for (int p = 0; p < 8; ++p) t += red[p][threadIdx.x];
        out[threadIdx.x] = t;
    }
}

extern "C" void kernel_launch(void* const* d_in, const int* in_sizes, int n_in,
                              void* d_out, int out_size, void* d_ws, size_t ws_size,
                              hipStream_t stream)
{
    const float* r    = (const float*)d_in[0];
    const float* xyz  = (const float*)d_in[1];
    const int*   prs  = (const int*)d_in[2];
    const int*   np   = (const int*)d_in[3];
    const float* sW1  = (const float*)d_in[4];
    const float* sb1  = (const float*)d_in[5];
    const float* sW2  = (const float*)d_in[6];
    const float* sb2  = (const float*)d_in[7];
    const float* sW3  = (const float*)d_in[8];
    const float* sb3  = (const float*)d_in[9];
    const float* eW1  = (const float*)d_in[10];
    const float* eb1  = (const float*)d_in[11];
    const float* eW2  = (const float*)d_in[12];
    const float* eb2  = (const float*)d_in[13];
    const float* eW3  = (const float*)d_in[14];
    const float* eb3  = (const float*)d_in[15];
    float* out = (float*)d_out;
    float* ws  = (float*)d_ws;
    const int P = in_sizes[2] / 2;

    float4* atomd = (float4*)ws;                 // 8192 float4 = 128 KB
    float*  bsums = ws + NATOM * 4;              // PB*64 f32

    size_t smem1 = (size_t)(4096 + 16384 + 8192 + 64) * 4;  // 114,944 B
    hipFuncSetAttribute((const void*)k_mlp_f2, hipFuncAttributeMaxDynamicSharedMemorySize, (int)smem1);
    k_mlp_f2<<<NATOM / 32, 512, smem1, stream>>>(r, xyz, sW1, sb1, eW1, eb1,
                                                 sW2, sb2, sW3, sb3,
                                                 eW2, eb2, eW3, eb3, atomd);

    size_t smem = (size_t)NATOM * 16 + 68 * 4 + NSEG * 4;   // 131,600 B
    hipFuncSetAttribute((const void*)k_pair, hipFuncAttributeMaxDynamicSharedMemorySize, (int)smem);
    k_pair<<<PB, PT, smem, stream>>>(atomd, prs, np, bsums, P);
    k_reduce<<<1, 512, 0, stream>>>(bsums, out);
}